// Round 16
// baseline (173.524 us; speedup 1.0000x reference)
//
#include <hip/hip_runtime.h>
#include <hip/hip_bf16.h>
#include <stdint.h>

typedef unsigned short u16;
typedef __bf16 bf16x8 __attribute__((ext_vector_type(8)));
typedef float f32x4 __attribute__((ext_vector_type(4)));
typedef float f32x16 __attribute__((ext_vector_type(16)));

#define NB 4
#define NT 2048
#define NC 1024
#define NH 16
#define ND 64
#define NM 8192  // NB*NT
#define KVB 64

__device__ __forceinline__ u16 f2bf(float f) {
  union { float f; uint32_t u; } v; v.f = f;
  return (u16)((v.u + 0x7FFFu + ((v.u >> 16) & 1u)) >> 16);
}

__device__ __forceinline__ uint32_t pk2(float a, float b) {
  union { __hip_bfloat162 h; uint32_t u; } c;
  c.h = __float22bfloat162_rn(float2{a, b});
  return c.u;
}

__device__ __forceinline__ float fexp2(float x) {
#if __has_builtin(__builtin_amdgcn_exp2f)
  return __builtin_amdgcn_exp2f(x);
#else
  return exp2f(x);
#endif
}

__device__ __forceinline__ void g2l16(const void* g, void* l) {
  __builtin_amdgcn_global_load_lds((__attribute__((address_space(1))) const void*)g,
                                   (__attribute__((address_space(3))) void*)l,
                                   16, 0, 0);
}

// ---------------- fp32 -> bf16 ----------------
__global__ __launch_bounds__(256) void cvt4(const float* __restrict__ in,
                                            u16* __restrict__ out, int n4) {
  int i = blockIdx.x * 256 + threadIdx.x;
  if (i >= n4) return;
  float4 v = ((const float4*)in)[i];
  ushort4 o;
  o.x = f2bf(v.x); o.y = f2bf(v.y); o.z = f2bf(v.z); o.w = f2bf(v.w);
  ((ushort4*)out)[i] = o;
}

__global__ __launch_bounds__(256) void cvtW(const float* __restrict__ w0,
                                            const float* __restrict__ w1,
                                            const float* __restrict__ w2,
                                            const float* __restrict__ w3,
                                            u16* o0, u16* o1, u16* o2, u16* o3) {
  const int y = blockIdx.y;
  const float* in = (y == 0) ? w0 : (y == 1) ? w1 : (y == 2) ? w2 : w3;
  u16* out = (y == 0) ? o0 : (y == 1) ? o1 : (y == 2) ? o2 : o3;
  int i = blockIdx.x * 256 + threadIdx.x;
  float4 v = ((const float4*)in)[i];
  ushort4 o;
  o.x = f2bf(v.x); o.y = f2bf(v.y); o.z = f2bf(v.z); o.w = f2bf(v.w);
  ((ushort4*)out)[i] = o;
}

// ---------------- GEMM: C[M,N] = A[M,K] @ W[N,K]^T + bias -----------------
// r14 loop (double-buffered, STAGE(next) first, one __syncthreads) with
// 32x32x16 MFMA: wave-tile 64x64 = 2x2 blocks of 32x32, 16 MFMA + 16
// ds_read_b128 per K-tile (MFMA pipe at the faster 32x32 rate, half the
// MFMA issue slots). Fragment/output layouts = flash5-verified.
// EPI 0: bf16; z=0 Q*(0.125*log2e) -> (B,H,T,D); z=1 K -> (B,H,T,D);
//        z=2 V -> (B,H,D,T).  EPI 1: fp32 row-major (M,1024).
template <int EPI>
__global__ __launch_bounds__(256, 2) void gemm33(
    const u16* __restrict__ A,
    const u16* __restrict__ W0, const u16* __restrict__ W1, const u16* __restrict__ W2,
    const float* __restrict__ b0, const float* __restrict__ b1, const float* __restrict__ b2,
    void* o0, void* o1, void* o2, int K) {
  const int z = blockIdx.z;
  const u16* Bw = (z == 0) ? W0 : ((z == 1) ? W1 : W2);
  const float* bias = (z == 0) ? b0 : ((z == 1) ? b1 : b2);
  void* outp = (z == 0) ? o0 : ((z == 1) ? o1 : o2);

  __shared__ __align__(16) char SB[2][32768];  // per buf: A 16K | B 16K

  const int lb = (blockIdx.x & 7) * (gridDim.x >> 3) + (blockIdx.x >> 3);
  const int m0 = (lb / 8) << 7;
  const int n0 = (lb % 8) << 7;
  const int t = threadIdx.x;
  const int wid = t >> 6, lane = t & 63;
  const int wm = wid >> 1, wn = wid & 1;
  const int ql = lane & 31, h5 = lane >> 5;
  const int swz = (ql & 7) << 4;

  // staging map (r12/r14-proven): thread t, unit j -> LDS byte t*16 + j*4096;
  // row=(t>>3)+j*32, chunk=t&7; pre-swizzled source col = (chunk^(row&7))*8.
  const int rr = t >> 3;
  const int sc = ((t & 7) ^ (rr & 7)) << 3;
  const u16* Asrc = A + (size_t)(m0 + rr) * K + sc;
  const u16* Bsrc = Bw + (size_t)(n0 + rr) * K + sc;

  f32x16 acc[2][2] = {};

  const int NTILES = K >> 6;  // 16

  auto STAGE = [&](int buf, int kt) {
#pragma unroll
    for (int j = 0; j < 4; ++j)
      g2l16(Asrc + (size_t)(j * 32) * K + kt * 64, SB[buf] + t * 16 + j * 4096);
#pragma unroll
    for (int j = 0; j < 4; ++j)
      g2l16(Bsrc + (size_t)(j * 32) * K + kt * 64,
            SB[buf] + 16384 + t * 16 + j * 4096);
  };

  STAGE(0, 0);
  __syncthreads();

#pragma unroll 2
  for (int kt = 0; kt < NTILES; ++kt) {
    const int cur = kt & 1;
    if (kt + 1 < NTILES) STAGE(cur ^ 1, kt + 1);  // issue BEFORE compute

    const char* Ab = SB[cur];
    const char* Bb = SB[cur] + 16384;
#pragma unroll
    for (int ks = 0; ks < 4; ++ks) {
      const int off = (ks * 32 + h5 * 16) ^ swz;
      bf16x8 a0 = *(const bf16x8*)(Ab + (wm * 64 + ql) * 128 + off);
      bf16x8 a1 = *(const bf16x8*)(Ab + (wm * 64 + 32 + ql) * 128 + off);
      bf16x8 b0v = *(const bf16x8*)(Bb + (wn * 64 + ql) * 128 + off);
      bf16x8 b1v = *(const bf16x8*)(Bb + (wn * 64 + 32 + ql) * 128 + off);
      __builtin_amdgcn_s_setprio(1);
      acc[0][0] = __builtin_amdgcn_mfma_f32_32x32x16_bf16(a0, b0v, acc[0][0], 0, 0, 0);
      acc[0][1] = __builtin_amdgcn_mfma_f32_32x32x16_bf16(a0, b1v, acc[0][1], 0, 0, 0);
      acc[1][0] = __builtin_amdgcn_mfma_f32_32x32x16_bf16(a1, b0v, acc[1][0], 0, 0, 0);
      acc[1][1] = __builtin_amdgcn_mfma_f32_32x32x16_bf16(a1, b1v, acc[1][1], 0, 0, 0);
      __builtin_amdgcn_s_setprio(0);
    }
    __syncthreads();
  }

  // C/D mapping (flash5-verified): col = ql (B row), row = (r&3)+8*(r>>2)+4*h5
  const float scl = (EPI == 0 && z == 0) ? 0.125f * 1.44269504089f : 1.0f;
#pragma unroll
  for (int fb = 0; fb < 2; ++fb) {
#pragma unroll
    for (int gb = 0; gb < 2; ++gb) {
#pragma unroll
      for (int r = 0; r < 16; ++r) {
        const int rg = m0 + wm * 64 + fb * 32 + (r & 3) + 8 * (r >> 2) + 4 * h5;
        const int cg = n0 + wn * 64 + gb * 32 + ql;
        const float v = (acc[fb][gb][r] + bias[cg]) * scl;
        if (EPI == 0) {
          const int bb = rg >> 11, tt = rg & (NT - 1);
          const int hh = cg >> 6, dd = cg & (ND - 1);
          size_t idx;
          if (z == 2)
            idx = ((size_t)(bb * NH + hh) * ND + dd) * NT + tt;   // V^T (B,H,D,T)
          else
            idx = ((size_t)(bb * NH + hh) * NT + tt) * ND + dd;   // (B,H,T,D)
          ((u16*)outp)[idx] = f2bf(v);
        } else {
          ((float*)outp)[(size_t)rg * NC + cg] = v;
        }
      }
    }
  }
}

// ---------------- causal flash attention, no-max softmax, uniform split ----
__global__ __launch_bounds__(512, 4) void flash5(const u16* __restrict__ Q,
                                                 const u16* __restrict__ Kg,
                                                 const u16* __restrict__ Vtg,
                                                 u16* __restrict__ Y) {
  __shared__ __align__(16) char LDS[65536];  // [grp][dbuf][K 8K | V 8K]

  const int n = blockIdx.x;
  const int xcd = n & 7, slot = n >> 3;
  const int bh = (xcd << 3) | (slot >> 3);   // 8 heads per XCD
  const int pt = slot & 7;
  const int qtB = 15 - pt;
  const int bb = bh >> 4, hh = bh & (NH - 1);
  const int tid = threadIdx.x;
  const int lane = tid & 63;
  const int grp = tid >> 8;                  // wave-group 0/1
  const int ws4 = (tid >> 6) & 3;            // 32-row slot within q-tile
  const int ql = lane & 31, h5 = lane >> 5;
  const int swz = (ql & 7) << 4;

  const u16* Qb = Q + (size_t)bh * NT * ND;
  const u16* Kb = Kg + (size_t)bh * NT * ND;
  const u16* Vb = Vtg + (size_t)bh * ND * NT;

  const int ntA = 2 * pt + 2;
  const int kvb1 = 15 - 2 * pt;              // group-1 KV base tile
  const int q0wB = (qtB << 7) + (ws4 << 5);

  int q0w = grp ? q0wB : (pt << 7) + (ws4 << 5);
  int qg = q0w + ql;

  bf16x8 qf[4];
#pragma unroll
  for (int s = 0; s < 4; ++s)
    qf[s] = *(const bf16x8*)(Qb + (size_t)qg * ND + s * 16 + h5 * 8);

  f32x16 O0 = 0.f, O1 = 0.f;
  float lr = 0.f;

  const int tl = tid & 255;
  char* myL = LDS + (grp << 15);

  auto kvof = [&](int it) {
    return grp ? (kvb1 + it) : (it < ntA ? it : it - ntA);
  };

  auto STAGE = [&](int buf, int kv) {
#pragma unroll
    for (int p = 0; p < 2; ++p) {
      const int c = tl + (p << 8);
      const int row = c >> 3;
      const int so = ((c & 7) << 4) ^ ((row & 7) << 4);  // pre-swizzled src
      g2l16((const char*)(Kb + (size_t)((kv << 6) + row) * ND) + so,
            myL + (buf << 14) + c * 16);
      g2l16((const char*)(Vb + (size_t)row * NT + (kv << 6)) + so,
            myL + (buf << 14) + 8192 + c * 16);
    }
  };

  auto WRITEY = [&](const f32x16& A0, const f32x16& A1, float inv, int qgl) {
    u16* Yb = Y + ((size_t)bb * NT + qgl) * NC + hh * ND;
#pragma unroll
    for (int rq = 0; rq < 16; rq += 4) {
      const int dbase = 2 * rq + 4 * h5;
      uint2 w2;
      w2.x = pk2(A0[rq] * inv, A0[rq + 1] * inv);
      w2.y = pk2(A0[rq + 2] * inv, A0[rq + 3] * inv);
      *(uint2*)(Yb + dbase) = w2;
      w2.x = pk2(A1[rq] * inv, A1[rq + 1] * inv);
      w2.y = pk2(A1[rq + 2] * inv, A1[rq + 3] * inv);
      *(uint2*)(Yb + 32 + dbase) = w2;
    }
  };

  STAGE(0, kvof(0));
  __syncthreads();

  for (int it = 0; it < 17; ++it) {
    const int buf = it & 1;
    if (it < 16) STAGE(buf ^ 1, kvof(it + 1));

    if (!grp && it == ntA) {  // A done: flush it, switch this wave to tile B
      const float lt = lr + __shfl_xor(lr, 32, 64);
      WRITEY(O0, O1, 1.f / lt, qg);
      O0 = 0.f; O1 = 0.f; lr = 0.f;
      q0w = q0wB; qg = q0w + ql;
#pragma unroll
      for (int s = 0; s < 4; ++s)
        qf[s] = *(const bf16x8*)(Qb + (size_t)qg * ND + s * 16 + h5 * 8);
    }

    const int kv0 = kvof(it) << 6;
    const char* Kc = myL + (buf << 14);
    const char* Vc = Kc + 8192;

    f32x16 Sa0 = 0.f, Sa1 = 0.f;
    __builtin_amdgcn_s_setprio(1);
#pragma unroll
    for (int s = 0; s < 4; ++s) {
      bf16x8 kf0 = *(const bf16x8*)(Kc + ql * 128 + ((s * 32 + h5 * 16) ^ swz));
      bf16x8 kf1 = *(const bf16x8*)(Kc + (32 + ql) * 128 + ((s * 32 + h5 * 16) ^ swz));
      Sa0 = __builtin_amdgcn_mfma_f32_32x32x16_bf16(kf0, qf[s], Sa0, 0, 0, 0);
      Sa1 = __builtin_amdgcn_mfma_f32_32x32x16_bf16(kf1, qf[s], Sa1, 0, 0, 0);
    }
    __builtin_amdgcn_s_setprio(0);

    if (kv0 + 63 > q0w) {  // diagonal: causal mask
#pragma unroll
      for (int r = 0; r < 16; ++r) {
        const int kvb = kv0 + (r & 3) + 8 * (r >> 2) + 4 * h5;
        if (kvb > qg) Sa0[r] = -3e38f;
        if (kvb + 32 > qg) Sa1[r] = -3e38f;
      }
    }

    float t0 = 0.f, t1 = 0.f, t2 = 0.f, t3 = 0.f;
#pragma unroll
    for (int r = 0; r < 16; r += 4) {
      const float a0 = fexp2(Sa0[r]),     a1 = fexp2(Sa0[r + 1]);
      const float a2 = fexp2(Sa0[r + 2]), a3 = fexp2(Sa0[r + 3]);
      const float b0 = fexp2(Sa1[r]),     b1 = fexp2(Sa1[r + 1]);
      const float b2 = fexp2(Sa1[r + 2]), b3 = fexp2(Sa1[r + 3]);
      Sa0[r] = a0; Sa0[r + 1] = a1; Sa0[r + 2] = a2; Sa0[r + 3] = a3;
      Sa1[r] = b0; Sa1[r + 1] = b1; Sa1[r + 2] = b2; Sa1[r + 3] = b3;
      t0 += a0 + b0; t1 += a1 + b1; t2 += a2 + b2; t3 += a3 + b3;
    }
    lr += (t0 + t1) + (t2 + t3);

    __builtin_amdgcn_s_setprio(1);
#pragma unroll
    for (int ks = 0; ks < 4; ++ks) {
      const int k0 = ks & 1;
      const f32x16& Sk = (ks < 2) ? Sa0 : Sa1;
      const uint32_t a0 = pk2(Sk[8 * k0],     Sk[8 * k0 + 1]);
      const uint32_t a1 = pk2(Sk[8 * k0 + 2], Sk[8 * k0 + 3]);
      const uint32_t b0 = pk2(Sk[8 * k0 + 4], Sk[8 * k0 + 5]);
      const uint32_t b1 = pk2(Sk[8 * k0 + 6], Sk[8 * k0 + 7]);
      const uint32_t c0 = h5 ? b0 : a0, c1 = h5 ? b1 : a1;
      const uint32_t d0 = h5 ? a0 : b0, d1 = h5 ? a1 : b1;
      const uint32_t x0 = __shfl_xor(d0, 32, 64);
      const uint32_t x1 = __shfl_xor(d1, 32, 64);
      union { uint32_t u[4]; bf16x8 v; } pf;
      pf.u[0] = h5 ? x0 : c0;
      pf.u[1] = h5 ? x1 : c1;
      pf.u[2] = h5 ? c0 : x0;
      pf.u[3] = h5 ? c1 : x1;
      bf16x8 vf0 = *(const bf16x8*)(Vc + ql * 128 + ((ks * 32 + h5 * 16) ^ swz));
      bf16x8 vf1 = *(const bf16x8*)(Vc + (32 + ql) * 128 + ((ks * 32 + h5 * 16) ^ swz));
      O0 = __builtin_amdgcn_mfma_f32_32x32x16_bf16(vf0, pf.v, O0, 0, 0, 0);
      O1 = __builtin_amdgcn_mfma_f32_32x32x16_bf16(vf1, pf.v, O1, 0, 0, 0);
    }
    __builtin_amdgcn_s_setprio(0);

    __syncthreads();
  }

  const int cslot = (ws4 << 6) + lane;
  char* cb = LDS + cslot * 136;
  if (!grp) {
#pragma unroll
    for (int j = 0; j < 8; ++j) {
      *(float2*)(cb + j * 8)      = float2{O0[2 * j], O0[2 * j + 1]};
      *(float2*)(cb + 64 + j * 8) = float2{O1[2 * j], O1[2 * j + 1]};
    }
    *(float*)(cb + 128) = lr;
  }
  __syncthreads();
  if (grp) {
#pragma unroll
    for (int j = 0; j < 8; ++j) {
      const float2 u = *(const float2*)(cb + j * 8);
      const float2 v = *(const float2*)(cb + 64 + j * 8);
      O0[2 * j] += u.x; O0[2 * j + 1] += u.y;
      O1[2 * j] += v.x; O1[2 * j + 1] += v.y;
    }
    lr += *(const float*)(cb + 128);
    const float lt = lr + __shfl_xor(lr, 32, 64);
    WRITEY(O0, O1, 1.f / lt, qg);
  }
}

extern "C" void kernel_launch(void* const* d_in, const int* in_sizes, int n_in,
                              void* d_out, int out_size, void* d_ws, size_t ws_size,
                              hipStream_t stream) {
  const float* x  = (const float*)d_in[0];
  const float* Wq = (const float*)d_in[1];
  const float* bq = (const float*)d_in[2];
  const float* Wk = (const float*)d_in[3];
  const float* bk = (const float*)d_in[4];
  const float* Wv = (const float*)d_in[5];
  const float* bv = (const float*)d_in[6];
  const float* Wo = (const float*)d_in[7];
  const float* bo = (const float*)d_in[8];

  const size_t SZ_X = (size_t)NM * NC * 2;  // 16 MB (bf16 activation)
  const size_t SZ_W = (size_t)NC * NC * 2;  // 2 MB  (bf16 weight)
  char* ws = (char*)d_ws;
  u16* xb  = (u16*)ws;
  u16* wqb = (u16*)(ws + SZ_X);
  u16* wkb = (u16*)(ws + SZ_X + 1 * SZ_W);
  u16* wvb = (u16*)(ws + SZ_X + 2 * SZ_W);
  u16* wob = (u16*)(ws + SZ_X + 3 * SZ_W);
  u16* vb  = (u16*)(ws + SZ_X + 4 * SZ_W);  // V^T (B,H,D,T)
  u16* yb  = (u16*)(ws + 2 * SZ_X + 4 * SZ_W);
  u16* qb = (u16*)d_out;
  u16* kb = (u16*)((char*)d_out + SZ_X);

  if (ws_size < 3 * SZ_X + 4 * SZ_W) return;  // fail loudly (poison stays)

  cvt4<<<dim3(NM * NC / 4 / 256), 256, 0, stream>>>(x, xb, NM * NC / 4);
  cvtW<<<dim3(NC * NC / 4 / 256, 4), 256, 0, stream>>>(Wq, Wk, Wv, Wo,
                                                       wqb, wkb, wvb, wob);

  gemm33<0><<<dim3(512, 1, 3), 256, 0, stream>>>(
      xb, wqb, wkb, wvb, bq, bk, bv, qb, kb, vb, NC);

  flash5<<<dim3(512), 512, 0, stream>>>(qb, kb, vb, yb);

  gemm33<1><<<dim3(512, 1, 1), 256, 0, stream>>>(
      yb, wob, wob, wob, bo, bo, bo, d_out, d_out, d_out, NC);
}

// Round 17
// 157.869 us; speedup vs baseline: 1.0992x; 1.0992x over previous
//
#include <hip/hip_runtime.h>
#include <hip/hip_bf16.h>
#include <stdint.h>

typedef unsigned short u16;
typedef __bf16 bf16x8 __attribute__((ext_vector_type(8)));
typedef float f32x4 __attribute__((ext_vector_type(4)));
typedef float f32x16 __attribute__((ext_vector_type(16)));

#define NB 4
#define NT 2048
#define NC 1024
#define NH 16
#define ND 64
#define NM 8192  // NB*NT
#define KVB 64

__device__ __forceinline__ u16 f2bf(float f) {
  union { float f; uint32_t u; } v; v.f = f;
  return (u16)((v.u + 0x7FFFu + ((v.u >> 16) & 1u)) >> 16);
}

__device__ __forceinline__ uint32_t pk2(float a, float b) {
  union { __hip_bfloat162 h; uint32_t u; } c;
  c.h = __float22bfloat162_rn(float2{a, b});
  return c.u;
}

__device__ __forceinline__ float fexp2(float x) {
#if __has_builtin(__builtin_amdgcn_exp2f)
  return __builtin_amdgcn_exp2f(x);
#else
  return exp2f(x);
#endif
}

__device__ __forceinline__ void g2l16(const void* g, void* l) {
  __builtin_amdgcn_global_load_lds((__attribute__((address_space(1))) const void*)g,
                                   (__attribute__((address_space(3))) void*)l,
                                   16, 0, 0);
}

// ---------------- fp32 -> bf16 ----------------
__global__ __launch_bounds__(256) void cvt4(const float* __restrict__ in,
                                            u16* __restrict__ out, int n4) {
  int i = blockIdx.x * 256 + threadIdx.x;
  if (i >= n4) return;
  float4 v = ((const float4*)in)[i];
  ushort4 o;
  o.x = f2bf(v.x); o.y = f2bf(v.y); o.z = f2bf(v.z); o.w = f2bf(v.w);
  ((ushort4*)out)[i] = o;
}

__global__ __launch_bounds__(256) void cvtW(const float* __restrict__ w0,
                                            const float* __restrict__ w1,
                                            const float* __restrict__ w2,
                                            const float* __restrict__ w3,
                                            u16* o0, u16* o1, u16* o2, u16* o3) {
  const int y = blockIdx.y;
  const float* in = (y == 0) ? w0 : (y == 1) ? w1 : (y == 2) ? w2 : w3;
  u16* out = (y == 0) ? o0 : (y == 1) ? o1 : (y == 2) ? o2 : o3;
  int i = blockIdx.x * 256 + threadIdx.x;
  float4 v = ((const float4*)in)[i];
  ushort4 o;
  o.x = f2bf(v.x); o.y = f2bf(v.y); o.z = f2bf(v.z); o.w = f2bf(v.w);
  ((ushort4*)out)[i] = o;
}

// ---------------- GEMM: C[M,N] = A[M,K] @ W[N,K]^T + bias -----------------
// flash5-style loop: double-buffered LDS (2x32KB), STAGE(next) issued FIRST
// in the iter body (latency hides under current-buffer compute), ONE
// __syncthreads per K-tile. BM=BN=128, BK=64, 4 waves (64x64 wave-tile),
// r12-proven 0-conflict slot-XOR layout + XCD swizzle. 2 blocks/CU.
// EPI 0: bf16; z=0 Q*(0.125*log2e) -> (B,H,T,D); z=1 K -> (B,H,T,D);
//        z=2 V -> (B,H,D,T).  EPI 1: fp32 row-major (M,1024).
template <int EPI>
__global__ __launch_bounds__(256, 2) void gemmDB(
    const u16* __restrict__ A,
    const u16* __restrict__ W0, const u16* __restrict__ W1, const u16* __restrict__ W2,
    const float* __restrict__ b0, const float* __restrict__ b1, const float* __restrict__ b2,
    void* o0, void* o1, void* o2, int K) {
  const int z = blockIdx.z;
  const u16* Bw = (z == 0) ? W0 : ((z == 1) ? W1 : W2);
  const float* bias = (z == 0) ? b0 : ((z == 1) ? b1 : b2);
  void* outp = (z == 0) ? o0 : ((z == 1) ? o1 : o2);

  __shared__ __align__(16) char SB[2][32768];  // per buf: A 16K | B 16K

  const int lb = (blockIdx.x & 7) * (gridDim.x >> 3) + (blockIdx.x >> 3);
  const int m0 = (lb / 8) << 7;
  const int n0 = (lb % 8) << 7;
  const int t = threadIdx.x;
  const int wid = t >> 6, lane = t & 63;
  const int wm = wid >> 1, wn = wid & 1;
  const int lo = lane & 15, hi = lane >> 4;

  // staging map (r12-proven): thread t, unit j -> LDS byte t*16 + j*4096;
  // row=(t>>3)+j*32, chunk=t&7; pre-swizzled source col = (chunk^(row&7))*8.
  const int rr = t >> 3;
  const int sc = ((t & 7) ^ (rr & 7)) << 3;
  const u16* Asrc = A + (size_t)(m0 + rr) * K + sc;
  const u16* Bsrc = Bw + (size_t)(n0 + rr) * K + sc;

  f32x4 acc[4][4] = {};

  const int NTILES = K >> 6;  // 16

  auto STAGE = [&](int buf, int kt) {
#pragma unroll
    for (int j = 0; j < 4; ++j)
      g2l16(Asrc + (size_t)(j * 32) * K + kt * 64, SB[buf] + t * 16 + j * 4096);
#pragma unroll
    for (int j = 0; j < 4; ++j)
      g2l16(Bsrc + (size_t)(j * 32) * K + kt * 64,
            SB[buf] + 16384 + t * 16 + j * 4096);
  };

  STAGE(0, 0);
  __syncthreads();

  for (int kt = 0; kt < NTILES; ++kt) {
    const int cur = kt & 1;
    if (kt + 1 < NTILES) STAGE(cur ^ 1, kt + 1);  // issue BEFORE compute

    const char* Ab = SB[cur];
    const char* Bb = SB[cur] + 16384;
#pragma unroll
    for (int kh = 0; kh < 2; ++kh) {
      const int slot = (((kh << 2) | hi) ^ (lo & 7)) << 4;
      bf16x8 af[4], bfr[4];
#pragma unroll
      for (int f = 0; f < 4; ++f)
        af[f] = *(const bf16x8*)(Ab + (wm * 64 + f * 16 + lo) * 128 + slot);
#pragma unroll
      for (int g = 0; g < 4; ++g)
        bfr[g] = *(const bf16x8*)(Bb + (wn * 64 + g * 16 + lo) * 128 + slot);
      __builtin_amdgcn_s_setprio(1);
#pragma unroll
      for (int f = 0; f < 4; ++f)
#pragma unroll
        for (int g = 0; g < 4; ++g)
          acc[f][g] = __builtin_amdgcn_mfma_f32_16x16x32_bf16(af[f], bfr[g],
                                                              acc[f][g], 0, 0, 0);
      __builtin_amdgcn_s_setprio(0);
    }
    __syncthreads();  // drains STAGE (latency already covered) + orders reads
  }

  const float scl = (EPI == 0 && z == 0) ? 0.125f * 1.44269504089f : 1.0f;
#pragma unroll
  for (int f = 0; f < 4; ++f) {
#pragma unroll
    for (int g = 0; g < 4; ++g) {
#pragma unroll
      for (int r = 0; r < 4; ++r) {
        const int rg = m0 + wm * 64 + f * 16 + hi * 4 + r;
        const int cg = n0 + wn * 64 + g * 16 + lo;
        const float v = (acc[f][g][r] + bias[cg]) * scl;
        if (EPI == 0) {
          const int bb = rg >> 11, tt = rg & (NT - 1);
          const int hh = cg >> 6, dd = cg & (ND - 1);
          size_t idx;
          if (z == 2)
            idx = ((size_t)(bb * NH + hh) * ND + dd) * NT + tt;   // V^T (B,H,D,T)
          else
            idx = ((size_t)(bb * NH + hh) * NT + tt) * ND + dd;   // (B,H,T,D)
          ((u16*)outp)[idx] = f2bf(v);
        } else {
          ((float*)outp)[(size_t)rg * NC + cg] = v;
        }
      }
    }
  }
}

// ---------------- causal flash attention, no-max softmax, uniform split ----
__global__ __launch_bounds__(512, 4) void flash5(const u16* __restrict__ Q,
                                                 const u16* __restrict__ Kg,
                                                 const u16* __restrict__ Vtg,
                                                 u16* __restrict__ Y) {
  __shared__ __align__(16) char LDS[65536];  // [grp][dbuf][K 8K | V 8K]

  const int n = blockIdx.x;
  const int xcd = n & 7, slot = n >> 3;
  const int bh = (xcd << 3) | (slot >> 3);   // 8 heads per XCD
  const int pt = slot & 7;
  const int qtB = 15 - pt;
  const int bb = bh >> 4, hh = bh & (NH - 1);
  const int tid = threadIdx.x;
  const int lane = tid & 63;
  const int grp = tid >> 8;                  // wave-group 0/1
  const int ws4 = (tid >> 6) & 3;            // 32-row slot within q-tile
  const int ql = lane & 31, h5 = lane >> 5;
  const int swz = (ql & 7) << 4;

  const u16* Qb = Q + (size_t)bh * NT * ND;
  const u16* Kb = Kg + (size_t)bh * NT * ND;
  const u16* Vb = Vtg + (size_t)bh * ND * NT;

  const int ntA = 2 * pt + 2;
  const int kvb1 = 15 - 2 * pt;              // group-1 KV base tile
  const int q0wB = (qtB << 7) + (ws4 << 5);

  int q0w = grp ? q0wB : (pt << 7) + (ws4 << 5);
  int qg = q0w + ql;

  bf16x8 qf[4];
#pragma unroll
  for (int s = 0; s < 4; ++s)
    qf[s] = *(const bf16x8*)(Qb + (size_t)qg * ND + s * 16 + h5 * 8);

  f32x16 O0 = 0.f, O1 = 0.f;
  float lr = 0.f;

  const int tl = tid & 255;
  char* myL = LDS + (grp << 15);

  auto kvof = [&](int it) {
    return grp ? (kvb1 + it) : (it < ntA ? it : it - ntA);
  };

  auto STAGE = [&](int buf, int kv) {
#pragma unroll
    for (int p = 0; p < 2; ++p) {
      const int c = tl + (p << 8);
      const int row = c >> 3;
      const int so = ((c & 7) << 4) ^ ((row & 7) << 4);  // pre-swizzled src
      g2l16((const char*)(Kb + (size_t)((kv << 6) + row) * ND) + so,
            myL + (buf << 14) + c * 16);
      g2l16((const char*)(Vb + (size_t)row * NT + (kv << 6)) + so,
            myL + (buf << 14) + 8192 + c * 16);
    }
  };

  auto WRITEY = [&](const f32x16& A0, const f32x16& A1, float inv, int qgl) {
    u16* Yb = Y + ((size_t)bb * NT + qgl) * NC + hh * ND;
#pragma unroll
    for (int rq = 0; rq < 16; rq += 4) {
      const int dbase = 2 * rq + 4 * h5;
      uint2 w2;
      w2.x = pk2(A0[rq] * inv, A0[rq + 1] * inv);
      w2.y = pk2(A0[rq + 2] * inv, A0[rq + 3] * inv);
      *(uint2*)(Yb + dbase) = w2;
      w2.x = pk2(A1[rq] * inv, A1[rq + 1] * inv);
      w2.y = pk2(A1[rq + 2] * inv, A1[rq + 3] * inv);
      *(uint2*)(Yb + 32 + dbase) = w2;
    }
  };

  STAGE(0, kvof(0));
  __syncthreads();

  for (int it = 0; it < 17; ++it) {
    const int buf = it & 1;
    if (it < 16) STAGE(buf ^ 1, kvof(it + 1));

    if (!grp && it == ntA) {  // A done: flush it, switch this wave to tile B
      const float lt = lr + __shfl_xor(lr, 32, 64);
      WRITEY(O0, O1, 1.f / lt, qg);
      O0 = 0.f; O1 = 0.f; lr = 0.f;
      q0w = q0wB; qg = q0w + ql;
#pragma unroll
      for (int s = 0; s < 4; ++s)
        qf[s] = *(const bf16x8*)(Qb + (size_t)qg * ND + s * 16 + h5 * 8);
    }

    const int kv0 = kvof(it) << 6;
    const char* Kc = myL + (buf << 14);
    const char* Vc = Kc + 8192;

    f32x16 Sa0 = 0.f, Sa1 = 0.f;
    __builtin_amdgcn_s_setprio(1);
#pragma unroll
    for (int s = 0; s < 4; ++s) {
      bf16x8 kf0 = *(const bf16x8*)(Kc + ql * 128 + ((s * 32 + h5 * 16) ^ swz));
      bf16x8 kf1 = *(const bf16x8*)(Kc + (32 + ql) * 128 + ((s * 32 + h5 * 16) ^ swz));
      Sa0 = __builtin_amdgcn_mfma_f32_32x32x16_bf16(kf0, qf[s], Sa0, 0, 0, 0);
      Sa1 = __builtin_amdgcn_mfma_f32_32x32x16_bf16(kf1, qf[s], Sa1, 0, 0, 0);
    }
    __builtin_amdgcn_s_setprio(0);

    if (kv0 + 63 > q0w) {  // diagonal: causal mask
#pragma unroll
      for (int r = 0; r < 16; ++r) {
        const int kvb = kv0 + (r & 3) + 8 * (r >> 2) + 4 * h5;
        if (kvb > qg) Sa0[r] = -3e38f;
        if (kvb + 32 > qg) Sa1[r] = -3e38f;
      }
    }

    float t0 = 0.f, t1 = 0.f, t2 = 0.f, t3 = 0.f;
#pragma unroll
    for (int r = 0; r < 16; r += 4) {
      const float a0 = fexp2(Sa0[r]),     a1 = fexp2(Sa0[r + 1]);
      const float a2 = fexp2(Sa0[r + 2]), a3 = fexp2(Sa0[r + 3]);
      const float b0 = fexp2(Sa1[r]),     b1 = fexp2(Sa1[r + 1]);
      const float b2 = fexp2(Sa1[r + 2]), b3 = fexp2(Sa1[r + 3]);
      Sa0[r] = a0; Sa0[r + 1] = a1; Sa0[r + 2] = a2; Sa0[r + 3] = a3;
      Sa1[r] = b0; Sa1[r + 1] = b1; Sa1[r + 2] = b2; Sa1[r + 3] = b3;
      t0 += a0 + b0; t1 += a1 + b1; t2 += a2 + b2; t3 += a3 + b3;
    }
    lr += (t0 + t1) + (t2 + t3);

    __builtin_amdgcn_s_setprio(1);
#pragma unroll
    for (int ks = 0; ks < 4; ++ks) {
      const int k0 = ks & 1;
      const f32x16& Sk = (ks < 2) ? Sa0 : Sa1;
      const uint32_t a0 = pk2(Sk[8 * k0],     Sk[8 * k0 + 1]);
      const uint32_t a1 = pk2(Sk[8 * k0 + 2], Sk[8 * k0 + 3]);
      const uint32_t b0 = pk2(Sk[8 * k0 + 4], Sk[8 * k0 + 5]);
      const uint32_t b1 = pk2(Sk[8 * k0 + 6], Sk[8 * k0 + 7]);
      const uint32_t c0 = h5 ? b0 : a0, c1 = h5 ? b1 : a1;
      const uint32_t d0 = h5 ? a0 : b0, d1 = h5 ? a1 : b1;
      const uint32_t x0 = __shfl_xor(d0, 32, 64);
      const uint32_t x1 = __shfl_xor(d1, 32, 64);
      union { uint32_t u[4]; bf16x8 v; } pf;
      pf.u[0] = h5 ? x0 : c0;
      pf.u[1] = h5 ? x1 : c1;
      pf.u[2] = h5 ? c0 : x0;
      pf.u[3] = h5 ? c1 : x1;
      bf16x8 vf0 = *(const bf16x8*)(Vc + ql * 128 + ((ks * 32 + h5 * 16) ^ swz));
      bf16x8 vf1 = *(const bf16x8*)(Vc + (32 + ql) * 128 + ((ks * 32 + h5 * 16) ^ swz));
      O0 = __builtin_amdgcn_mfma_f32_32x32x16_bf16(vf0, pf.v, O0, 0, 0, 0);
      O1 = __builtin_amdgcn_mfma_f32_32x32x16_bf16(vf1, pf.v, O1, 0, 0, 0);
    }
    __builtin_amdgcn_s_setprio(0);

    __syncthreads();
  }

  const int cslot = (ws4 << 6) + lane;
  char* cb = LDS + cslot * 136;
  if (!grp) {
#pragma unroll
    for (int j = 0; j < 8; ++j) {
      *(float2*)(cb + j * 8)      = float2{O0[2 * j], O0[2 * j + 1]};
      *(float2*)(cb + 64 + j * 8) = float2{O1[2 * j], O1[2 * j + 1]};
    }
    *(float*)(cb + 128) = lr;
  }
  __syncthreads();
  if (grp) {
#pragma unroll
    for (int j = 0; j < 8; ++j) {
      const float2 u = *(const float2*)(cb + j * 8);
      const float2 v = *(const float2*)(cb + 64 + j * 8);
      O0[2 * j] += u.x; O0[2 * j + 1] += u.y;
      O1[2 * j] += v.x; O1[2 * j + 1] += v.y;
    }
    lr += *(const float*)(cb + 128);
    const float lt = lr + __shfl_xor(lr, 32, 64);
    WRITEY(O0, O1, 1.f / lt, qg);
  }
}

extern "C" void kernel_launch(void* const* d_in, const int* in_sizes, int n_in,
                              void* d_out, int out_size, void* d_ws, size_t ws_size,
                              hipStream_t stream) {
  const float* x  = (const float*)d_in[0];
  const float* Wq = (const float*)d_in[1];
  const float* bq = (const float*)d_in[2];
  const float* Wk = (const float*)d_in[3];
  const float* bk = (const float*)d_in[4];
  const float* Wv = (const float*)d_in[5];
  const float* bv = (const float*)d_in[6];
  const float* Wo = (const float*)d_in[7];
  const float* bo = (const float*)d_in[8];

  const size_t SZ_X = (size_t)NM * NC * 2;  // 16 MB (bf16 activation)
  const size_t SZ_W = (size_t)NC * NC * 2;  // 2 MB  (bf16 weight)
  char* ws = (char*)d_ws;
  u16* xb  = (u16*)ws;
  u16* wqb = (u16*)(ws + SZ_X);
  u16* wkb = (u16*)(ws + SZ_X + 1 * SZ_W);
  u16* wvb = (u16*)(ws + SZ_X + 2 * SZ_W);
  u16* wob = (u16*)(ws + SZ_X + 3 * SZ_W);
  u16* vb  = (u16*)(ws + SZ_X + 4 * SZ_W);  // V^T (B,H,D,T)
  u16* yb  = (u16*)(ws + 2 * SZ_X + 4 * SZ_W);
  u16* qb = (u16*)d_out;
  u16* kb = (u16*)((char*)d_out + SZ_X);

  if (ws_size < 3 * SZ_X + 4 * SZ_W) return;  // fail loudly (poison stays)

  cvt4<<<dim3(NM * NC / 4 / 256), 256, 0, stream>>>(x, xb, NM * NC / 4);
  cvtW<<<dim3(NC * NC / 4 / 256, 4), 256, 0, stream>>>(Wq, Wk, Wv, Wo,
                                                       wqb, wkb, wvb, wob);

  gemmDB<0><<<dim3(512, 1, 3), 256, 0, stream>>>(
      xb, wqb, wkb, wvb, bq, bk, bv, qb, kb, vb, NC);

  flash5<<<dim3(512), 512, 0, stream>>>(qb, kb, vb, yb);

  gemmDB<1><<<dim3(512, 1, 1), 256, 0, stream>>>(
      yb, wob, wob, wob, bo, bo, bo, d_out, d_out, d_out, NC);
}

// Round 18
// 155.962 us; speedup vs baseline: 1.1126x; 1.0122x over previous
//
#include <hip/hip_runtime.h>
#include <hip/hip_bf16.h>
#include <stdint.h>

typedef unsigned short u16;
typedef __bf16 bf16x8 __attribute__((ext_vector_type(8)));
typedef float f32x4 __attribute__((ext_vector_type(4)));
typedef float f32x16 __attribute__((ext_vector_type(16)));

#define NB 4
#define NT 2048
#define NC 1024
#define NH 16
#define ND 64
#define NM 8192  // NB*NT
#define KVB 64

__device__ __forceinline__ u16 f2bf(float f) {
  union { float f; uint32_t u; } v; v.f = f;
  return (u16)((v.u + 0x7FFFu + ((v.u >> 16) & 1u)) >> 16);
}

__device__ __forceinline__ uint32_t pk2(float a, float b) {
  union { __hip_bfloat162 h; uint32_t u; } c;
  c.h = __float22bfloat162_rn(float2{a, b});
  return c.u;
}

__device__ __forceinline__ float fexp2(float x) {
#if __has_builtin(__builtin_amdgcn_exp2f)
  return __builtin_amdgcn_exp2f(x);
#else
  return exp2f(x);
#endif
}

__device__ __forceinline__ void g2l16(const void* g, void* l) {
  __builtin_amdgcn_global_load_lds((__attribute__((address_space(1))) const void*)g,
                                   (__attribute__((address_space(3))) void*)l,
                                   16, 0, 0);
}

// ---------------- fp32 -> bf16, all 5 tensors in ONE launch ----------------
// blocks [0,8192): x (8M floats); [8192,12288): W0..W3 (1M floats each).
__global__ __launch_bounds__(256) void cvtAll(
    const float* __restrict__ x,
    const float* __restrict__ w0, const float* __restrict__ w1,
    const float* __restrict__ w2, const float* __restrict__ w3,
    u16* __restrict__ ox, u16* o0, u16* o1, u16* o2, u16* o3) {
  const int b = blockIdx.x;
  const float* in;
  u16* out;
  int i;
  if (b < 8192) {
    in = x; out = ox; i = b * 256 + threadIdx.x;
  } else {
    const int w = (b - 8192) >> 10;
    const int wb = (b - 8192) & 1023;
    in = (w == 0) ? w0 : (w == 1) ? w1 : (w == 2) ? w2 : w3;
    out = (w == 0) ? o0 : (w == 1) ? o1 : (w == 2) ? o2 : o3;
    i = wb * 256 + threadIdx.x;
  }
  float4 v = ((const float4*)in)[i];
  ushort4 o;
  o.x = f2bf(v.x); o.y = f2bf(v.y); o.z = f2bf(v.z); o.w = f2bf(v.w);
  ((ushort4*)out)[i] = o;
}

// ---------------- GEMM: C[M,N] = A[M,K] @ W[N,K]^T + bias -----------------
// flash5-style loop: double-buffered LDS (2x32KB), STAGE(next) issued FIRST
// in the iter body (latency hides under current-buffer compute), ONE
// __syncthreads per K-tile. BM=BN=128, BK=64, 4 waves (64x64 wave-tile),
// r12-proven 0-conflict slot-XOR layout + XCD swizzle. 2 blocks/CU.
// EPI 0: bf16; z=0 Q*(0.125*log2e) -> (B,H,T,D); z=1 K -> (B,H,T,D);
//        z=2 V -> (B,H,D,T).  EPI 1: fp32 row-major (M,1024).
template <int EPI>
__global__ __launch_bounds__(256, 2) void gemmDB(
    const u16* __restrict__ A,
    const u16* __restrict__ W0, const u16* __restrict__ W1, const u16* __restrict__ W2,
    const float* __restrict__ b0, const float* __restrict__ b1, const float* __restrict__ b2,
    void* o0, void* o1, void* o2, int K) {
  const int z = blockIdx.z;
  const u16* Bw = (z == 0) ? W0 : ((z == 1) ? W1 : W2);
  const float* bias = (z == 0) ? b0 : ((z == 1) ? b1 : b2);
  void* outp = (z == 0) ? o0 : ((z == 1) ? o1 : o2);

  __shared__ __align__(16) char SB[2][32768];  // per buf: A 16K | B 16K

  const int lb = (blockIdx.x & 7) * (gridDim.x >> 3) + (blockIdx.x >> 3);
  const int m0 = (lb / 8) << 7;
  const int n0 = (lb % 8) << 7;
  const int t = threadIdx.x;
  const int wid = t >> 6, lane = t & 63;
  const int wm = wid >> 1, wn = wid & 1;
  const int lo = lane & 15, hi = lane >> 4;

  // staging map (r12-proven): thread t, unit j -> LDS byte t*16 + j*4096;
  // row=(t>>3)+j*32, chunk=t&7; pre-swizzled source col = (chunk^(row&7))*8.
  const int rr = t >> 3;
  const int sc = ((t & 7) ^ (rr & 7)) << 3;
  const u16* Asrc = A + (size_t)(m0 + rr) * K + sc;
  const u16* Bsrc = Bw + (size_t)(n0 + rr) * K + sc;

  f32x4 acc[4][4] = {};

  const int NTILES = K >> 6;  // 16

  auto STAGE = [&](int buf, int kt) {
#pragma unroll
    for (int j = 0; j < 4; ++j)
      g2l16(Asrc + (size_t)(j * 32) * K + kt * 64, SB[buf] + t * 16 + j * 4096);
#pragma unroll
    for (int j = 0; j < 4; ++j)
      g2l16(Bsrc + (size_t)(j * 32) * K + kt * 64,
            SB[buf] + 16384 + t * 16 + j * 4096);
  };

  STAGE(0, 0);
  __syncthreads();

  for (int kt = 0; kt < NTILES; ++kt) {
    const int cur = kt & 1;
    if (kt + 1 < NTILES) STAGE(cur ^ 1, kt + 1);  // issue BEFORE compute

    const char* Ab = SB[cur];
    const char* Bb = SB[cur] + 16384;
#pragma unroll
    for (int kh = 0; kh < 2; ++kh) {
      const int slot = (((kh << 2) | hi) ^ (lo & 7)) << 4;
      bf16x8 af[4], bfr[4];
#pragma unroll
      for (int f = 0; f < 4; ++f)
        af[f] = *(const bf16x8*)(Ab + (wm * 64 + f * 16 + lo) * 128 + slot);
#pragma unroll
      for (int g = 0; g < 4; ++g)
        bfr[g] = *(const bf16x8*)(Bb + (wn * 64 + g * 16 + lo) * 128 + slot);
      __builtin_amdgcn_s_setprio(1);
#pragma unroll
      for (int f = 0; f < 4; ++f)
#pragma unroll
        for (int g = 0; g < 4; ++g)
          acc[f][g] = __builtin_amdgcn_mfma_f32_16x16x32_bf16(af[f], bfr[g],
                                                              acc[f][g], 0, 0, 0);
      __builtin_amdgcn_s_setprio(0);
    }
    __syncthreads();  // drains STAGE (latency already covered) + orders reads
  }

  const float scl = (EPI == 0 && z == 0) ? 0.125f * 1.44269504089f : 1.0f;
#pragma unroll
  for (int f = 0; f < 4; ++f) {
#pragma unroll
    for (int g = 0; g < 4; ++g) {
#pragma unroll
      for (int r = 0; r < 4; ++r) {
        const int rg = m0 + wm * 64 + f * 16 + hi * 4 + r;
        const int cg = n0 + wn * 64 + g * 16 + lo;
        const float v = (acc[f][g][r] + bias[cg]) * scl;
        if (EPI == 0) {
          const int bb = rg >> 11, tt = rg & (NT - 1);
          const int hh = cg >> 6, dd = cg & (ND - 1);
          size_t idx;
          if (z == 2)
            idx = ((size_t)(bb * NH + hh) * ND + dd) * NT + tt;   // V^T (B,H,D,T)
          else
            idx = ((size_t)(bb * NH + hh) * NT + tt) * ND + dd;   // (B,H,T,D)
          ((u16*)outp)[idx] = f2bf(v);
        } else {
          ((float*)outp)[(size_t)rg * NC + cg] = v;
        }
      }
    }
  }
}

// ---------------- causal flash attention, no-max softmax, uniform split ----
__global__ __launch_bounds__(512, 4) void flash5(const u16* __restrict__ Q,
                                                 const u16* __restrict__ Kg,
                                                 const u16* __restrict__ Vtg,
                                                 u16* __restrict__ Y) {
  __shared__ __align__(16) char LDS[65536];  // [grp][dbuf][K 8K | V 8K]

  const int n = blockIdx.x;
  const int xcd = n & 7, slot = n >> 3;
  const int bh = (xcd << 3) | (slot >> 3);   // 8 heads per XCD
  const int pt = slot & 7;
  const int qtB = 15 - pt;
  const int bb = bh >> 4, hh = bh & (NH - 1);
  const int tid = threadIdx.x;
  const int lane = tid & 63;
  const int grp = tid >> 8;                  // wave-group 0/1
  const int ws4 = (tid >> 6) & 3;            // 32-row slot within q-tile
  const int ql = lane & 31, h5 = lane >> 5;
  const int swz = (ql & 7) << 4;

  const u16* Qb = Q + (size_t)bh * NT * ND;
  const u16* Kb = Kg + (size_t)bh * NT * ND;
  const u16* Vb = Vtg + (size_t)bh * ND * NT;

  const int ntA = 2 * pt + 2;
  const int kvb1 = 15 - 2 * pt;              // group-1 KV base tile
  const int q0wB = (qtB << 7) + (ws4 << 5);

  int q0w = grp ? q0wB : (pt << 7) + (ws4 << 5);
  int qg = q0w + ql;

  bf16x8 qf[4];
#pragma unroll
  for (int s = 0; s < 4; ++s)
    qf[s] = *(const bf16x8*)(Qb + (size_t)qg * ND + s * 16 + h5 * 8);

  f32x16 O0 = 0.f, O1 = 0.f;
  float lr = 0.f;

  const int tl = tid & 255;
  char* myL = LDS + (grp << 15);

  auto kvof = [&](int it) {
    return grp ? (kvb1 + it) : (it < ntA ? it : it - ntA);
  };

  auto STAGE = [&](int buf, int kv) {
#pragma unroll
    for (int p = 0; p < 2; ++p) {
      const int c = tl + (p << 8);
      const int row = c >> 3;
      const int so = ((c & 7) << 4) ^ ((row & 7) << 4);  // pre-swizzled src
      g2l16((const char*)(Kb + (size_t)((kv << 6) + row) * ND) + so,
            myL + (buf << 14) + c * 16);
      g2l16((const char*)(Vb + (size_t)row * NT + (kv << 6)) + so,
            myL + (buf << 14) + 8192 + c * 16);
    }
  };

  auto WRITEY = [&](const f32x16& A0, const f32x16& A1, float inv, int qgl) {
    u16* Yb = Y + ((size_t)bb * NT + qgl) * NC + hh * ND;
#pragma unroll
    for (int rq = 0; rq < 16; rq += 4) {
      const int dbase = 2 * rq + 4 * h5;
      uint2 w2;
      w2.x = pk2(A0[rq] * inv, A0[rq + 1] * inv);
      w2.y = pk2(A0[rq + 2] * inv, A0[rq + 3] * inv);
      *(uint2*)(Yb + dbase) = w2;
      w2.x = pk2(A1[rq] * inv, A1[rq + 1] * inv);
      w2.y = pk2(A1[rq + 2] * inv, A1[rq + 3] * inv);
      *(uint2*)(Yb + 32 + dbase) = w2;
    }
  };

  STAGE(0, kvof(0));
  __syncthreads();

  for (int it = 0; it < 17; ++it) {
    const int buf = it & 1;
    if (it < 16) STAGE(buf ^ 1, kvof(it + 1));

    if (!grp && it == ntA) {  // A done: flush it, switch this wave to tile B
      const float lt = lr + __shfl_xor(lr, 32, 64);
      WRITEY(O0, O1, 1.f / lt, qg);
      O0 = 0.f; O1 = 0.f; lr = 0.f;
      q0w = q0wB; qg = q0w + ql;
#pragma unroll
      for (int s = 0; s < 4; ++s)
        qf[s] = *(const bf16x8*)(Qb + (size_t)qg * ND + s * 16 + h5 * 8);
    }

    const int kv0 = kvof(it) << 6;
    const char* Kc = myL + (buf << 14);
    const char* Vc = Kc + 8192;

    f32x16 Sa0 = 0.f, Sa1 = 0.f;
    __builtin_amdgcn_s_setprio(1);
#pragma unroll
    for (int s = 0; s < 4; ++s) {
      bf16x8 kf0 = *(const bf16x8*)(Kc + ql * 128 + ((s * 32 + h5 * 16) ^ swz));
      bf16x8 kf1 = *(const bf16x8*)(Kc + (32 + ql) * 128 + ((s * 32 + h5 * 16) ^ swz));
      Sa0 = __builtin_amdgcn_mfma_f32_32x32x16_bf16(kf0, qf[s], Sa0, 0, 0, 0);
      Sa1 = __builtin_amdgcn_mfma_f32_32x32x16_bf16(kf1, qf[s], Sa1, 0, 0, 0);
    }
    __builtin_amdgcn_s_setprio(0);

    if (kv0 + 63 > q0w) {  // diagonal: causal mask
#pragma unroll
      for (int r = 0; r < 16; ++r) {
        const int kvb = kv0 + (r & 3) + 8 * (r >> 2) + 4 * h5;
        if (kvb > qg) Sa0[r] = -3e38f;
        if (kvb + 32 > qg) Sa1[r] = -3e38f;
      }
    }

    float t0 = 0.f, t1 = 0.f, t2 = 0.f, t3 = 0.f;
#pragma unroll
    for (int r = 0; r < 16; r += 4) {
      const float a0 = fexp2(Sa0[r]),     a1 = fexp2(Sa0[r + 1]);
      const float a2 = fexp2(Sa0[r + 2]), a3 = fexp2(Sa0[r + 3]);
      const float b0 = fexp2(Sa1[r]),     b1 = fexp2(Sa1[r + 1]);
      const float b2 = fexp2(Sa1[r + 2]), b3 = fexp2(Sa1[r + 3]);
      Sa0[r] = a0; Sa0[r + 1] = a1; Sa0[r + 2] = a2; Sa0[r + 3] = a3;
      Sa1[r] = b0; Sa1[r + 1] = b1; Sa1[r + 2] = b2; Sa1[r + 3] = b3;
      t0 += a0 + b0; t1 += a1 + b1; t2 += a2 + b2; t3 += a3 + b3;
    }
    lr += (t0 + t1) + (t2 + t3);

    __builtin_amdgcn_s_setprio(1);
#pragma unroll
    for (int ks = 0; ks < 4; ++ks) {
      const int k0 = ks & 1;
      const f32x16& Sk = (ks < 2) ? Sa0 : Sa1;
      const uint32_t a0 = pk2(Sk[8 * k0],     Sk[8 * k0 + 1]);
      const uint32_t a1 = pk2(Sk[8 * k0 + 2], Sk[8 * k0 + 3]);
      const uint32_t b0 = pk2(Sk[8 * k0 + 4], Sk[8 * k0 + 5]);
      const uint32_t b1 = pk2(Sk[8 * k0 + 6], Sk[8 * k0 + 7]);
      const uint32_t c0 = h5 ? b0 : a0, c1 = h5 ? b1 : a1;
      const uint32_t d0 = h5 ? a0 : b0, d1 = h5 ? a1 : b1;
      const uint32_t x0 = __shfl_xor(d0, 32, 64);
      const uint32_t x1 = __shfl_xor(d1, 32, 64);
      union { uint32_t u[4]; bf16x8 v; } pf;
      pf.u[0] = h5 ? x0 : c0;
      pf.u[1] = h5 ? x1 : c1;
      pf.u[2] = h5 ? c0 : x0;
      pf.u[3] = h5 ? c1 : x1;
      bf16x8 vf0 = *(const bf16x8*)(Vc + ql * 128 + ((ks * 32 + h5 * 16) ^ swz));
      bf16x8 vf1 = *(const bf16x8*)(Vc + (32 + ql) * 128 + ((ks * 32 + h5 * 16) ^ swz));
      O0 = __builtin_amdgcn_mfma_f32_32x32x16_bf16(vf0, pf.v, O0, 0, 0, 0);
      O1 = __builtin_amdgcn_mfma_f32_32x32x16_bf16(vf1, pf.v, O1, 0, 0, 0);
    }
    __builtin_amdgcn_s_setprio(0);

    __syncthreads();
  }

  const int cslot = (ws4 << 6) + lane;
  char* cb = LDS + cslot * 136;
  if (!grp) {
#pragma unroll
    for (int j = 0; j < 8; ++j) {
      *(float2*)(cb + j * 8)      = float2{O0[2 * j], O0[2 * j + 1]};
      *(float2*)(cb + 64 + j * 8) = float2{O1[2 * j], O1[2 * j + 1]};
    }
    *(float*)(cb + 128) = lr;
  }
  __syncthreads();
  if (grp) {
#pragma unroll
    for (int j = 0; j < 8; ++j) {
      const float2 u = *(const float2*)(cb + j * 8);
      const float2 v = *(const float2*)(cb + 64 + j * 8);
      O0[2 * j] += u.x; O0[2 * j + 1] += u.y;
      O1[2 * j] += v.x; O1[2 * j + 1] += v.y;
    }
    lr += *(const float*)(cb + 128);
    const float lt = lr + __shfl_xor(lr, 32, 64);
    WRITEY(O0, O1, 1.f / lt, qg);
  }
}

extern "C" void kernel_launch(void* const* d_in, const int* in_sizes, int n_in,
                              void* d_out, int out_size, void* d_ws, size_t ws_size,
                              hipStream_t stream) {
  const float* x  = (const float*)d_in[0];
  const float* Wq = (const float*)d_in[1];
  const float* bq = (const float*)d_in[2];
  const float* Wk = (const float*)d_in[3];
  const float* bk = (const float*)d_in[4];
  const float* Wv = (const float*)d_in[5];
  const float* bv = (const float*)d_in[6];
  const float* Wo = (const float*)d_in[7];
  const float* bo = (const float*)d_in[8];

  const size_t SZ_X = (size_t)NM * NC * 2;  // 16 MB (bf16 activation)
  const size_t SZ_W = (size_t)NC * NC * 2;  // 2 MB  (bf16 weight)
  char* ws = (char*)d_ws;
  u16* xb  = (u16*)ws;
  u16* wqb = (u16*)(ws + SZ_X);
  u16* wkb = (u16*)(ws + SZ_X + 1 * SZ_W);
  u16* wvb = (u16*)(ws + SZ_X + 2 * SZ_W);
  u16* wob = (u16*)(ws + SZ_X + 3 * SZ_W);
  u16* vb  = (u16*)(ws + SZ_X + 4 * SZ_W);  // V^T (B,H,D,T)
  u16* yb  = (u16*)(ws + 2 * SZ_X + 4 * SZ_W);
  u16* qb = (u16*)d_out;
  u16* kb = (u16*)((char*)d_out + SZ_X);

  if (ws_size < 3 * SZ_X + 4 * SZ_W) return;  // fail loudly (poison stays)

  // one launch: x (8192 blocks) + 4 weight matrices (4096 blocks)
  cvtAll<<<dim3(12288), 256, 0, stream>>>(x, Wq, Wk, Wv, Wo,
                                          xb, wqb, wkb, wvb, wob);

  gemmDB<0><<<dim3(512, 1, 3), 256, 0, stream>>>(
      xb, wqb, wkb, wvb, bq, bk, bv, qb, kb, vb, NC);

  flash5<<<dim3(512), 512, 0, stream>>>(qb, kb, vb, yb);

  gemmDB<1><<<dim3(512, 1, 1), 256, 0, stream>>>(
      yb, wob, wob, wob, bo, bo, bo, d_out, d_out, d_out, NC);
}